// Round 1
// baseline (340.618 us; speedup 1.0000x reference)
//
#include <hip/hip_runtime.h>
#include <cstdint>
#include <cstddef>

#define GEPS 1e-6f

using bf16x8 = __attribute__((ext_vector_type(8))) short;   // 8 bf16 = 4 VGPRs
using f32x4  = __attribute__((ext_vector_type(4))) float;   // MFMA C/D frag

__device__ inline ushort f2bf(float x) {
    union { float f; uint32_t u; } v; v.f = x;
    uint32_t r = (v.u + 0x7fffu + ((v.u >> 16) & 1u)) >> 16;  // RNE
    return (ushort)r;
}
__device__ inline float bf2f(ushort b) {
    union { float f; uint32_t u; } v; v.u = ((uint32_t)b) << 16;
    return v.f;
}

// ---------------------------------------------------------------------------
// Kernel 1: pack weights to bf16 + reorganize bias table to [h][dy][dx]
//   Wbuf[(proj*256+co)*2304 + k] = bf16(w_proj[co][k]),  k = ci*9 + kh*3 + kw
//   wo_bf[o*256+c] = bf16(wo[o][c])
//   bias_r[h*3969 + dy*63 + dx] = bias_table[(dy*63+dx)*8 + h]
// ---------------------------------------------------------------------------
__global__ void pack_k(const float* __restrict__ wq, const float* __restrict__ wk,
                       const float* __restrict__ wv, const float* __restrict__ wo,
                       const float* __restrict__ btab,
                       ushort* __restrict__ Wbuf, ushort* __restrict__ wo_bf,
                       float* __restrict__ bias_r)
{
    int i = blockIdx.x * 256 + threadIdx.x;
    if (i < 768 * 2304) {
        int n = i / 2304, k = i - n * 2304;
        int proj = n >> 8, co = n & 255;
        const float* src = (proj == 0) ? wq : ((proj == 1) ? wk : wv);
        Wbuf[i] = f2bf(src[co * 2304 + k]);
        return;
    }
    int j = i - 768 * 2304;
    if (j < 65536) { wo_bf[j] = f2bf(wo[j]); return; }
    int t = j - 65536;
    if (t < 8 * 3969) {
        int h = t / 3969, rk = t - h * 3969;
        bias_r[h * 3969 + rk] = btab[rk * 8 + h];
    }
}

// ---------------------------------------------------------------------------
// Kernel 2: im2col patches, shared by all three convs.
//   Abuf[m][ci*9+tap] = x[b][ci][py+kh-1][px+kw-1] (zero pad), bf16
//   block = one m (= b*1024 + spatial), thread = ci
// ---------------------------------------------------------------------------
__global__ void im2col_k(const float* __restrict__ x, ushort* __restrict__ Ab)
{
    int m = blockIdx.x;
    int ci = threadIdx.x;
    int b = m >> 10, px = m & 1023, py = px >> 5, pxx = px & 31;
    const float* xs = x + (size_t)(b * 256 + ci) * 1024;
    ushort* dst = Ab + (size_t)m * 2304 + ci * 9;
#pragma unroll
    for (int kh = 0; kh < 3; ++kh) {
        int yy = py + kh - 1;
#pragma unroll
        for (int kw = 0; kw < 3; ++kw) {
            int xx = pxx + kw - 1;
            float v = (yy >= 0 && yy < 32 && xx >= 0 && xx < 32) ? xs[yy * 32 + xx] : 0.f;
            dst[kh * 3 + kw] = f2bf(v);
        }
    }
}

// ---------------------------------------------------------------------------
// Kernel 3/6: generic bf16 GEMM  C[M,N] = A[M,K] * B[N,K]^T
//   128x128 tile, BK=64, 4 waves each owning a 64x64 subtile of 4x4 MFMAs.
//   LDS rows padded to 72 bf16 (+8) to break power-of-2 bank strides.
//   mode 0 (conv): store bf16 C + atomic per-(proj,b) sum/sumsq for GroupNorm
//   mode 1 (out-proj, roles swapped M=o_channels, N=b*px):
//           store fp32 d_out[b][o][px] = C + bias[o]   (coalesced in px)
// ---------------------------------------------------------------------------
__global__ __launch_bounds__(256, 2) void gemm_bt(
    const ushort* __restrict__ A, const ushort* __restrict__ B,
    int M, int N, int K,
    ushort* __restrict__ Cbf, float* __restrict__ stats,
    float* __restrict__ Cout, const float* __restrict__ bias, int mode)
{
    __shared__ __align__(16) ushort As[128 * 72];
    __shared__ __align__(16) ushort Bs[128 * 72];
    int tid = threadIdx.x;
    int mbase = blockIdx.x * 128, nbase = blockIdx.y * 128;
    int wave = tid >> 6, lane = tid & 63;
    int wm = wave & 1, wn = wave >> 1;
    int quad = lane >> 4, c = lane & 15;

    f32x4 acc[4][4];
#pragma unroll
    for (int i = 0; i < 4; ++i)
#pragma unroll
        for (int j = 0; j < 4; ++j) acc[i][j] = (f32x4){0.f, 0.f, 0.f, 0.f};

    for (int kb = 0; kb < K; kb += 64) {
        __syncthreads();
#pragma unroll
        for (int R = 0; R < 4; ++R) {
            int s = R * 256 + tid;
            int row = s >> 3, cc = s & 7;
            *(uint4*)&As[row * 72 + cc * 8] =
                *(const uint4*)(A + (size_t)(mbase + row) * K + kb + cc * 8);
            *(uint4*)&Bs[row * 72 + cc * 8] =
                *(const uint4*)(B + (size_t)(nbase + row) * K + kb + cc * 8);
        }
        __syncthreads();
#pragma unroll
        for (int kq = 0; kq < 2; ++kq) {
            bf16x8 af[4], bfr[4];
#pragma unroll
            for (int i = 0; i < 4; ++i) {
                af[i]  = *(const bf16x8*)&As[(wm * 64 + i * 16 + c) * 72 + kq * 32 + quad * 8];
                bfr[i] = *(const bf16x8*)&Bs[(wn * 64 + i * 16 + c) * 72 + kq * 32 + quad * 8];
            }
#pragma unroll
            for (int i = 0; i < 4; ++i)
#pragma unroll
                for (int j = 0; j < 4; ++j)
                    acc[i][j] = __builtin_amdgcn_mfma_f32_16x16x32_bf16(
                        af[i], bfr[j], acc[i][j], 0, 0, 0);
        }
    }

    if (mode == 0) {
        float s1 = 0.f, s2 = 0.f;
#pragma unroll
        for (int i = 0; i < 4; ++i) {
            int mrow = mbase + wm * 64 + i * 16 + quad * 4;
#pragma unroll
            for (int j = 0; j < 4; ++j) {
                int ncol = nbase + wn * 64 + j * 16 + c;
#pragma unroll
                for (int r = 0; r < 4; ++r) {
                    float v = acc[i][j][r];
                    Cbf[(size_t)(mrow + r) * N + ncol] = f2bf(v);
                    s1 += v; s2 += v * v;
                }
            }
        }
#pragma unroll
        for (int off = 32; off > 0; off >>= 1) {
            s1 += __shfl_down(s1, off, 64);
            s2 += __shfl_down(s2, off, 64);
        }
        if (lane == 0) {
            int proj = nbase >> 8, bidx = mbase >> 10;
            atomicAdd(&stats[(proj * 8 + bidx) * 2 + 0], s1);
            atomicAdd(&stats[(proj * 8 + bidx) * 2 + 1], s2);
        }
    } else {
#pragma unroll
        for (int i = 0; i < 4; ++i) {
            int mrow0 = mbase + wm * 64 + i * 16 + quad * 4;
#pragma unroll
            for (int j = 0; j < 4; ++j) {
                int ncol = nbase + wn * 64 + j * 16 + c;
                int bb = ncol >> 10, px = ncol & 1023;
#pragma unroll
                for (int r = 0; r < 4; ++r) {
                    int o = mrow0 + r;
                    Cout[((size_t)bb * 256 + o) * 1024 + px] = acc[i][j][r] + bias[o];
                }
            }
        }
    }
}

// ---------------------------------------------------------------------------
// Kernel 4: GroupNorm(1) + exact GELU + head reshape, fp32 math, bf16 out.
//   q/k -> [b][h][n][d] (K-major for QK^T A/B frags)
//   v   -> [b][h][d][n] transposed (so PV B-operand V^T[d][key] is contiguous)
// ---------------------------------------------------------------------------
__global__ void gn_k(const ushort* __restrict__ conv, const float* __restrict__ stats,
                     const float* __restrict__ gq, const float* __restrict__ bq,
                     const float* __restrict__ gk, const float* __restrict__ bk,
                     const float* __restrict__ gv, const float* __restrict__ bv,
                     ushort* __restrict__ qb, ushort* __restrict__ kb2,
                     ushort* __restrict__ vt)
{
    int t = blockIdx.x * 256 + threadIdx.x;     // 8192 * 96 threads
    int m = t / 96;
    int nn = (t - m * 96) * 8;                  // n offset in [0,768), 8-aligned
    int proj = nn >> 8, co = nn & 255;
    int b = m >> 10, px = m & 1023;
    float s1 = stats[(proj * 8 + b) * 2 + 0];
    float s2 = stats[(proj * 8 + b) * 2 + 1];
    const float Ninv = 1.f / 262144.f;          // 256*1024 elements per (proj,b)
    float mu = s1 * Ninv;
    float var = fmaxf(s2 * Ninv - mu * mu, 0.f);
    float rsig = rsqrtf(var + GEPS);
    const float* gam = (proj == 0) ? gq : ((proj == 1) ? gk : gv);
    const float* bet = (proj == 0) ? bq : ((proj == 1) ? bk : bv);

    union { uint4 v; ushort s[8]; } in, outp;
    in.v = *(const uint4*)(conv + (size_t)m * 768 + nn);
#pragma unroll
    for (int e = 0; e < 8; ++e) {
        int cc = co + e;
        float xv = bf2f(in.s[e]);
        float xn = (xv - mu) * rsig * gam[cc] + bet[cc];
        float ge = 0.5f * xn * (1.f + erff(xn * 0.70710678118654752f));
        outp.s[e] = f2bf(ge);
    }
    int h = co >> 5, d = co & 31;               // 8 consecutive d within one head
    if (proj == 0) {
        *(uint4*)(qb + ((((size_t)b * 8 + h) * 1024 + px) * 32 + d)) = outp.v;
    } else if (proj == 1) {
        *(uint4*)(kb2 + ((((size_t)b * 8 + h) * 1024 + px) * 32 + d)) = outp.v;
    } else {
#pragma unroll
        for (int e = 0; e < 8; ++e)
            vt[(((size_t)b * 8 + h) * 32 + d + e) * 1024 + px] = outp.s[e];
    }
}

// ---------------------------------------------------------------------------
// Kernel 5: fused flash attention with relative-position bias (no scale!).
//   block = 4 waves; wave owns 16 q-rows, loops 1024 keys in 64-key tiles.
//   S = Q*K^T via 4 MFMAs (K=32 = full d); online softmax with 16-lane
//   butterflies; P -> bf16 -> LDS (row stride 72) -> A-frag; PV via 4 MFMAs.
// ---------------------------------------------------------------------------
__global__ __launch_bounds__(256, 2) void attn_k(
    const ushort* __restrict__ qb, const ushort* __restrict__ kb,
    const ushort* __restrict__ vt, const float* __restrict__ bias_r,
    ushort* __restrict__ attnout)
{
    __shared__ __align__(16) ushort Pl[4 * 16 * 72];
    int tid = threadIdx.x, wave = tid >> 6, lane = tid & 63;
    int quad = lane >> 4, c = lane & 15;
    int bh = blockIdx.y;               // b*8 + h
    int h = bh & 7, b = bh >> 3;
    int qbase = blockIdx.x * 64 + wave * 16;

    const ushort* Q  = qb + (size_t)bh * 1024 * 32;
    const ushort* Kp = kb + (size_t)bh * 1024 * 32;
    const ushort* Vt = vt + (size_t)bh * 32 * 1024;
    const float* brh = bias_r + h * 3969;
    ushort* Pw = Pl + wave * 16 * 72;

    bf16x8 qf = *(const bf16x8*)&Q[(qbase + c) * 32 + quad * 8];

    float m_[4] = {-1e30f, -1e30f, -1e30f, -1e30f};
    float l_[4] = {0.f, 0.f, 0.f, 0.f};
    f32x4 Of0 = {0.f, 0.f, 0.f, 0.f}, Of1 = {0.f, 0.f, 0.f, 0.f};
    int qy[4], qx[4];
#pragma unroll
    for (int r = 0; r < 4; ++r) {
        int qr = qbase + quad * 4 + r;
        qy[r] = qr >> 5; qx[r] = qr & 31;
    }

    for (int kb64 = 0; kb64 < 1024; kb64 += 64) {
        f32x4 S[4];
        f32x4 zf = {0.f, 0.f, 0.f, 0.f};
#pragma unroll
        for (int f = 0; f < 4; ++f) {
            bf16x8 kf = *(const bf16x8*)&Kp[(kb64 + f * 16 + c) * 32 + quad * 8];
            S[f] = __builtin_amdgcn_mfma_f32_16x16x32_bf16(qf, kf, zf, 0, 0, 0);
        }
        // relative-position bias
#pragma unroll
        for (int f = 0; f < 4; ++f) {
            int key = kb64 + f * 16 + c;
            int ky = key >> 5, kx = key & 31;
#pragma unroll
            for (int r = 0; r < 4; ++r)
                S[f][r] += brh[(qy[r] - ky + 31) * 63 + (qx[r] - kx + 31)];
        }
        // row max (over this 64-key tile)
        float mx[4];
#pragma unroll
        for (int r = 0; r < 4; ++r) {
            float v = fmaxf(fmaxf(S[0][r], S[1][r]), fmaxf(S[2][r], S[3][r]));
            v = fmaxf(v, __shfl_xor(v, 1, 64));
            v = fmaxf(v, __shfl_xor(v, 2, 64));
            v = fmaxf(v, __shfl_xor(v, 4, 64));
            v = fmaxf(v, __shfl_xor(v, 8, 64));
            mx[r] = v;
        }
        float alpha[4];
#pragma unroll
        for (int r = 0; r < 4; ++r) {
            float mn = fmaxf(m_[r], mx[r]);
            alpha[r] = __expf(m_[r] - mn);
            m_[r] = mn;
        }
        float rs[4];
#pragma unroll
        for (int r = 0; r < 4; ++r) {
            float s = 0.f;
#pragma unroll
            for (int f = 0; f < 4; ++f) {
                float p = __expf(S[f][r] - m_[r]);
                S[f][r] = p;
                s += p;
            }
            s += __shfl_xor(s, 1, 64);
            s += __shfl_xor(s, 2, 64);
            s += __shfl_xor(s, 4, 64);
            s += __shfl_xor(s, 8, 64);
            rs[r] = s;
        }
#pragma unroll
        for (int r = 0; r < 4; ++r) {
            l_[r] = l_[r] * alpha[r] + rs[r];
            Of0[r] *= alpha[r];
            Of1[r] *= alpha[r];
        }
        // P (C-layout) -> LDS -> A-layout
        __syncthreads();
#pragma unroll
        for (int f = 0; f < 4; ++f)
#pragma unroll
            for (int r = 0; r < 4; ++r)
                Pw[(quad * 4 + r) * 72 + f * 16 + c] = f2bf(S[f][r]);
        __syncthreads();
#pragma unroll
        for (int kc = 0; kc < 2; ++kc) {
            bf16x8 pf = *(const bf16x8*)&Pw[c * 72 + kc * 32 + quad * 8];
            bf16x8 vf0 = *(const bf16x8*)&Vt[(c) * 1024 + kb64 + kc * 32 + quad * 8];
            Of0 = __builtin_amdgcn_mfma_f32_16x16x32_bf16(pf, vf0, Of0, 0, 0, 0);
            bf16x8 vf1 = *(const bf16x8*)&Vt[(16 + c) * 1024 + kb64 + kc * 32 + quad * 8];
            Of1 = __builtin_amdgcn_mfma_f32_16x16x32_bf16(pf, vf1, Of1, 0, 0, 0);
        }
    }
#pragma unroll
    for (int r = 0; r < 4; ++r) {
        float inv = 1.f / l_[r];
        int qr = qbase + quad * 4 + r;
        size_t base = ((size_t)b * 1024 + qr) * 256 + h * 32;
        attnout[base + c]      = f2bf(Of0[r] * inv);
        attnout[base + 16 + c] = f2bf(Of1[r] * inv);
    }
}

// ---------------------------------------------------------------------------
extern "C" void kernel_launch(void* const* d_in, const int* in_sizes, int n_in,
                              void* d_out, int out_size, void* d_ws, size_t ws_size,
                              hipStream_t stream)
{
    const float* x    = (const float*)d_in[0];
    const float* wq   = (const float*)d_in[1];
    const float* wk   = (const float*)d_in[2];
    const float* wv   = (const float*)d_in[3];
    const float* gq   = (const float*)d_in[4];
    const float* bq   = (const float*)d_in[5];
    const float* gk   = (const float*)d_in[6];
    const float* bk   = (const float*)d_in[7];
    const float* gv   = (const float*)d_in[8];
    const float* bv   = (const float*)d_in[9];
    const float* btab = (const float*)d_in[10];
    const float* wo   = (const float*)d_in[11];
    const float* bo   = (const float*)d_in[12];
    float* out = (float*)d_out;

    char* w = (char*)d_ws;
    size_t off = 0;
    auto alloc = [&](size_t bytes) -> char* {
        char* p = w + off;
        off += (bytes + 255) & ~(size_t)255;
        return p;
    };
    ushort* Abuf    = (ushort*)alloc(8192ull * 2304 * 2);   // im2col patches
    ushort* Wbuf    = (ushort*)alloc(768ull * 2304 * 2);    // concat conv weights
    ushort* wo_bf   = (ushort*)alloc(65536ull * 2);         // out-proj weight
    float*  bias_r  = (float*)alloc(8ull * 3969 * 4);       // [h][dy][dx]
    ushort* convout = (ushort*)alloc(8192ull * 768 * 2);    // conv GEMM out
    float*  stats   = (float*)alloc(256);                   // [proj][b][sum,sumsq]
    ushort* qb      = (ushort*)alloc(8ull * 8 * 1024 * 32 * 2);
    ushort* kb2     = (ushort*)alloc(8ull * 8 * 1024 * 32 * 2);
    ushort* vt      = (ushort*)alloc(8ull * 8 * 32 * 1024 * 2);
    ushort* attnout = (ushort*)alloc(8192ull * 256 * 2);

    hipMemsetAsync(stats, 0, 256, stream);
    pack_k<<<7293, 256, 0, stream>>>(wq, wk, wv, wo, btab, Wbuf, wo_bf, bias_r);
    im2col_k<<<8192, 256, 0, stream>>>(x, Abuf);
    gemm_bt<<<dim3(64, 6), 256, 0, stream>>>(Abuf, Wbuf, 8192, 768, 2304,
                                             convout, stats, nullptr, nullptr, 0);
    gn_k<<<3072, 256, 0, stream>>>(convout, stats, gq, bq, gk, bk, gv, bv,
                                   qb, kb2, vt);
    attn_k<<<dim3(16, 64), 256, 0, stream>>>(qb, kb2, vt, bias_r, attnout);
    gemm_bt<<<dim3(2, 64), 256, 0, stream>>>(wo_bf, attnout, 256, 8192, 256,
                                             nullptr, nullptr, out, bo, 1);
}

// Round 2
// 269.098 us; speedup vs baseline: 1.2658x; 1.2658x over previous
//
#include <hip/hip_runtime.h>
#include <cstdint>
#include <cstddef>

#define GEPS 1e-6f

using bf16x8 = __attribute__((ext_vector_type(8))) short;   // 8 bf16 = 4 VGPRs
using f32x4  = __attribute__((ext_vector_type(4))) float;   // MFMA C/D frag

__device__ inline ushort f2bf(float x) {
    union { float f; uint32_t u; } v; v.f = x;
    uint32_t r = (v.u + 0x7fffu + ((v.u >> 16) & 1u)) >> 16;  // RNE
    return (ushort)r;
}
__device__ inline float bf2f(ushort b) {
    union { float f; uint32_t u; } v; v.u = ((uint32_t)b) << 16;
    return v.f;
}

// async global->LDS, 16 bytes per lane. LDS dest = wave-uniform base + lane*16.
__device__ inline void gll16(const void* g, void* l) {
    __builtin_amdgcn_global_load_lds(
        (const __attribute__((address_space(1))) void*)g,
        (__attribute__((address_space(3))) void*)l, 16, 0, 0);
}

// ---------------------------------------------------------------------------
// Kernel 1: pack weights to bf16 (k reordered TAP-MAJOR: k = tap*256 + ci)
//   + reorganize bias table to [h][dy][dx]
// ---------------------------------------------------------------------------
__global__ void pack_k(const float* __restrict__ wq, const float* __restrict__ wk,
                       const float* __restrict__ wv, const float* __restrict__ wo,
                       const float* __restrict__ btab,
                       ushort* __restrict__ Wbuf, ushort* __restrict__ wo_bf,
                       float* __restrict__ bias_r)
{
    int i = blockIdx.x * 256 + threadIdx.x;
    if (i < 768 * 2304) {
        int n = i / 2304, k = i - n * 2304;
        int proj = n >> 8, co = n & 255;
        int tap = k >> 8, ci = k & 255;          // tap-major k
        const float* src = (proj == 0) ? wq : ((proj == 1) ? wk : wv);
        Wbuf[i] = f2bf(src[co * 2304 + ci * 9 + tap]);
        return;
    }
    int j = i - 768 * 2304;
    if (j < 65536) { wo_bf[j] = f2bf(wo[j]); return; }
    int t = j - 65536;
    if (t < 8 * 3969) {
        int h = t / 3969, rk = t - h * 3969;
        bias_r[h * 3969 + rk] = btab[rk * 8 + h];
    }
}

// ---------------------------------------------------------------------------
// Kernel 2: im2col via LDS transpose. Block = (b, py): one output image row.
//   Load x[b][:, py-1..py+1, :] coalesced (96 contiguous floats per ci),
//   stage bf16 in LDS [yy][xx+1][ci] with zero pad columns/rows, then emit
//   Ab[m][k] (k = tap*256+ci) as PERFECTLY LINEAR uint4 stores:
//   global addr = m0*2304 + idx*8, idx = px*288 + tap*32 + ci8.
// ---------------------------------------------------------------------------
__global__ __launch_bounds__(256) void im2col_k(const float* __restrict__ x,
                                                ushort* __restrict__ Ab)
{
    __shared__ __align__(16) ushort Xs[3 * 34 * 256];   // [yy][xx+1][ci] 51 KB
    int tid = threadIdx.x;
    int blk = blockIdx.x;               // b*32 + py
    int b = blk >> 5, py = blk & 31;

    // zero-pad columns xx=-1 and xx=32
#pragma unroll
    for (int yy = 0; yy < 3; ++yy) {
        Xs[(yy * 34 + 0) * 256 + tid] = 0;
        Xs[(yy * 34 + 33) * 256 + tid] = 0;
    }

    // load+convert+transpose: 6144 float4 units, 24 per thread
#pragma unroll
    for (int it = 0; it < 24; ++it) {
        int j = it * 256 + tid;
        int ci = j / 24;
        int o = (j - ci * 24) * 4;      // float offset within 96 (3 rows x 32)
        int yy = o >> 5, xx = o & 31;
        int row = py - 1 + yy;
        float4 v = make_float4(0.f, 0.f, 0.f, 0.f);
        if (row >= 0 && row < 32)
            v = *(const float4*)&x[((size_t)(b * 256 + ci)) * 1024 + row * 32 + xx];
        int base = (yy * 34 + xx + 1) * 256 + ci;
        Xs[base + 0 * 256] = f2bf(v.x);
        Xs[base + 1 * 256] = f2bf(v.y);
        Xs[base + 2 * 256] = f2bf(v.z);
        Xs[base + 3 * 256] = f2bf(v.w);
    }
    __syncthreads();

    // emit: 9216 uint4 per block, 36 per thread, fully coalesced stores
    ushort* dst = Ab + (size_t)(b * 1024 + py * 32) * 2304;
#pragma unroll
    for (int it = 0; it < 36; ++it) {
        int idx = it * 256 + tid;       // 0..9215
        int ci8 = idx & 31;
        int tp = (idx >> 5) % 9;
        int px = idx / 288;
        int kh = tp / 3, kw = tp - kh * 3;
        uint4 p = *(const uint4*)&Xs[(kh * 34 + px + kw) * 256 + ci8 * 8];
        *(uint4*)&dst[(size_t)idx * 8] = p;
    }
}

// ---------------------------------------------------------------------------
// Kernel 3/6: generic bf16 GEMM  C[M,N] = A[M,K] * B[N,K]^T
//   128x128 tile, BK=64. Staging via global_load_lds width=16 (no VGPR
//   round-trip); LDS unpadded 128x64 with XOR column-block swizzle
//   (cc^(row&7)) applied on the GLOBAL side so fragment ds_read_b128s are
//   2-way aliased (free) instead of 16-way conflicted.
//   mode 0 (conv): store fp32 C + atomic per-(proj,b) sum/sumsq for GroupNorm
//   mode 1 (out-proj): store fp32 d_out[b][o][px] = C + bias[o]
// ---------------------------------------------------------------------------
__global__ __launch_bounds__(256, 2) void gemm_bt(
    const ushort* __restrict__ A, const ushort* __restrict__ B,
    int M, int N, int K,
    float* __restrict__ Cconv, float* __restrict__ stats,
    float* __restrict__ Cout, const float* __restrict__ bias, int mode)
{
    __shared__ __align__(16) ushort As[128 * 64];
    __shared__ __align__(16) ushort Bs[128 * 64];
    int tid = threadIdx.x;
    int mbase = blockIdx.x * 128, nbase = blockIdx.y * 128;
    int wave = tid >> 6, lane = tid & 63;
    int wm = wave & 1, wn = wave >> 1;
    int quad = lane >> 4, c = lane & 15;

    int row_s = tid >> 3;               // staging row (R=0), +32 per R
    int cc8 = (tid & 7) ^ (row_s & 7);  // swizzled global column-block
    ushort* ldsA = As + (size_t)(wave * 64) * 8;   // wave-uniform dest base
    ushort* ldsB = Bs + (size_t)(wave * 64) * 8;

    f32x4 acc[4][4];
#pragma unroll
    for (int i = 0; i < 4; ++i)
#pragma unroll
        for (int j = 0; j < 4; ++j) acc[i][j] = (f32x4){0.f, 0.f, 0.f, 0.f};

    for (int kb = 0; kb < K; kb += 64) {
        __syncthreads();
#pragma unroll
        for (int R = 0; R < 4; ++R) {
            int row = R * 32 + row_s;
            gll16(A + (size_t)(mbase + row) * K + kb + cc8 * 8,
                  ldsA + (size_t)R * 256 * 8);
            gll16(B + (size_t)(nbase + row) * K + kb + cc8 * 8,
                  ldsB + (size_t)R * 256 * 8);
        }
        __syncthreads();                // drains vmcnt (compiler-inserted)
#pragma unroll
        for (int kq = 0; kq < 2; ++kq) {
            bf16x8 af[4], bfr[4];
            int sw = ((kq * 4 + quad) ^ (c & 7)) * 8;
#pragma unroll
            for (int i = 0; i < 4; ++i) {
                af[i]  = *(const bf16x8*)&As[(wm * 64 + i * 16 + c) * 64 + sw];
                bfr[i] = *(const bf16x8*)&Bs[(wn * 64 + i * 16 + c) * 64 + sw];
            }
#pragma unroll
            for (int i = 0; i < 4; ++i)
#pragma unroll
                for (int j = 0; j < 4; ++j)
                    acc[i][j] = __builtin_amdgcn_mfma_f32_16x16x32_bf16(
                        af[i], bfr[j], acc[i][j], 0, 0, 0);
        }
    }

    if (mode == 0) {
        float s1 = 0.f, s2 = 0.f;
#pragma unroll
        for (int i = 0; i < 4; ++i) {
            int mrow = mbase + wm * 64 + i * 16 + quad * 4;
#pragma unroll
            for (int j = 0; j < 4; ++j) {
                int ncol = nbase + wn * 64 + j * 16 + c;
#pragma unroll
                for (int r = 0; r < 4; ++r) {
                    float v = acc[i][j][r];
                    Cconv[(size_t)(mrow + r) * N + ncol] = v;
                    s1 += v; s2 += v * v;
                }
            }
        }
#pragma unroll
        for (int off = 32; off > 0; off >>= 1) {
            s1 += __shfl_down(s1, off, 64);
            s2 += __shfl_down(s2, off, 64);
        }
        if (lane == 0) {
            int proj = nbase >> 8, bidx = mbase >> 10;
            atomicAdd(&stats[(proj * 8 + bidx) * 2 + 0], s1);
            atomicAdd(&stats[(proj * 8 + bidx) * 2 + 1], s2);
        }
    } else {
#pragma unroll
        for (int i = 0; i < 4; ++i) {
            int mrow0 = mbase + wm * 64 + i * 16 + quad * 4;
#pragma unroll
            for (int j = 0; j < 4; ++j) {
                int ncol = nbase + wn * 64 + j * 16 + c;
                int bb = ncol >> 10, px = ncol & 1023;
#pragma unroll
                for (int r = 0; r < 4; ++r) {
                    int o = mrow0 + r;
                    Cout[((size_t)bb * 256 + o) * 1024 + px] = acc[i][j][r] + bias[o];
                }
            }
        }
    }
}

// ---------------------------------------------------------------------------
// Kernel 4: GroupNorm(1) + exact GELU + head reshape; fp32 conv input.
//   q/k -> [b][h][n][d] ; v -> [b][h][d][n] transposed
// ---------------------------------------------------------------------------
__global__ void gn_k(const float* __restrict__ conv, const float* __restrict__ stats,
                     const float* __restrict__ gq, const float* __restrict__ bq,
                     const float* __restrict__ gk, const float* __restrict__ bk,
                     const float* __restrict__ gv, const float* __restrict__ bv,
                     ushort* __restrict__ qb, ushort* __restrict__ kb2,
                     ushort* __restrict__ vt)
{
    int t = blockIdx.x * 256 + threadIdx.x;     // 8192 * 96 threads
    int m = t / 96;
    int nn = (t - m * 96) * 8;                  // n offset in [0,768), 8-aligned
    int proj = nn >> 8, co = nn & 255;
    int b = m >> 10, px = m & 1023;
    float s1 = stats[(proj * 8 + b) * 2 + 0];
    float s2 = stats[(proj * 8 + b) * 2 + 1];
    const float Ninv = 1.f / 262144.f;          // 256*1024 elements per (proj,b)
    float mu = s1 * Ninv;
    float var = fmaxf(s2 * Ninv - mu * mu, 0.f);
    float rsig = rsqrtf(var + GEPS);
    const float* gam = (proj == 0) ? gq : ((proj == 1) ? gk : gv);
    const float* bet = (proj == 0) ? bq : ((proj == 1) ? bk : bv);

    const float* src = conv + (size_t)m * 768 + nn;
    float4 in0 = *(const float4*)src;
    float4 in1 = *(const float4*)(src + 4);
    float xv[8] = {in0.x, in0.y, in0.z, in0.w, in1.x, in1.y, in1.z, in1.w};
    union { uint4 v; ushort s[8]; } outp;
#pragma unroll
    for (int e = 0; e < 8; ++e) {
        int cc = co + e;
        float xn = (xv[e] - mu) * rsig * gam[cc] + bet[cc];
        float ge = 0.5f * xn * (1.f + erff(xn * 0.70710678118654752f));
        outp.s[e] = f2bf(ge);
    }
    int h = co >> 5, d = co & 31;               // 8 consecutive d within one head
    if (proj == 0) {
        *(uint4*)(qb + ((((size_t)b * 8 + h) * 1024 + px) * 32 + d)) = outp.v;
    } else if (proj == 1) {
        *(uint4*)(kb2 + ((((size_t)b * 8 + h) * 1024 + px) * 32 + d)) = outp.v;
    } else {
#pragma unroll
        for (int e = 0; e < 8; ++e)
            vt[(((size_t)b * 8 + h) * 32 + d + e) * 1024 + px] = outp.s[e];
    }
}

// ---------------------------------------------------------------------------
// Kernel 5: fused flash attention with relative-position bias (no scale).
//   wave owns 16 q-rows; 64-key tiles; online softmax; P->LDS->A-frag
//   round-trip is PER-WAVE (own slice) so no __syncthreads needed.
// ---------------------------------------------------------------------------
__global__ __launch_bounds__(256, 2) void attn_k(
    const ushort* __restrict__ qb, const ushort* __restrict__ kb,
    const ushort* __restrict__ vt, const float* __restrict__ bias_r,
    ushort* __restrict__ attnout)
{
    __shared__ __align__(16) ushort Pl[4 * 16 * 72];
    int tid = threadIdx.x, wave = tid >> 6, lane = tid & 63;
    int quad = lane >> 4, c = lane & 15;
    int bh = blockIdx.y;               // b*8 + h
    int h = bh & 7, b = bh >> 3;
    int qbase = blockIdx.x * 64 + wave * 16;

    const ushort* Q  = qb + (size_t)bh * 1024 * 32;
    const ushort* Kp = kb + (size_t)bh * 1024 * 32;
    const ushort* Vt = vt + (size_t)bh * 32 * 1024;
    const float* brh = bias_r + h * 3969;
    ushort* Pw = Pl + wave * 16 * 72;

    bf16x8 qf = *(const bf16x8*)&Q[(qbase + c) * 32 + quad * 8];

    float m_[4] = {-1e30f, -1e30f, -1e30f, -1e30f};
    float l_[4] = {0.f, 0.f, 0.f, 0.f};
    f32x4 Of0 = {0.f, 0.f, 0.f, 0.f}, Of1 = {0.f, 0.f, 0.f, 0.f};
    int qy[4], qx[4];
#pragma unroll
    for (int r = 0; r < 4; ++r) {
        int qr = qbase + quad * 4 + r;
        qy[r] = qr >> 5; qx[r] = qr & 31;
    }

    for (int kb64 = 0; kb64 < 1024; kb64 += 64) {
        f32x4 S[4];
        f32x4 zf = {0.f, 0.f, 0.f, 0.f};
#pragma unroll
        for (int f = 0; f < 4; ++f) {
            bf16x8 kf = *(const bf16x8*)&Kp[(kb64 + f * 16 + c) * 32 + quad * 8];
            S[f] = __builtin_amdgcn_mfma_f32_16x16x32_bf16(qf, kf, zf, 0, 0, 0);
        }
#pragma unroll
        for (int f = 0; f < 4; ++f) {
            int key = kb64 + f * 16 + c;
            int ky = key >> 5, kx = key & 31;
#pragma unroll
            for (int r = 0; r < 4; ++r)
                S[f][r] += brh[(qy[r] - ky + 31) * 63 + (qx[r] - kx + 31)];
        }
        float mx[4];
#pragma unroll
        for (int r = 0; r < 4; ++r) {
            float v = fmaxf(fmaxf(S[0][r], S[1][r]), fmaxf(S[2][r], S[3][r]));
            v = fmaxf(v, __shfl_xor(v, 1, 64));
            v = fmaxf(v, __shfl_xor(v, 2, 64));
            v = fmaxf(v, __shfl_xor(v, 4, 64));
            v = fmaxf(v, __shfl_xor(v, 8, 64));
            mx[r] = v;
        }
        float alpha[4];
#pragma unroll
        for (int r = 0; r < 4; ++r) {
            float mn = fmaxf(m_[r], mx[r]);
            alpha[r] = __expf(m_[r] - mn);
            m_[r] = mn;
        }
        float rs[4];
#pragma unroll
        for (int r = 0; r < 4; ++r) {
            float s = 0.f;
#pragma unroll
            for (int f = 0; f < 4; ++f) {
                float p = __expf(S[f][r] - m_[r]);
                S[f][r] = p;
                s += p;
            }
            s += __shfl_xor(s, 1, 64);
            s += __shfl_xor(s, 2, 64);
            s += __shfl_xor(s, 4, 64);
            s += __shfl_xor(s, 8, 64);
            rs[r] = s;
        }
#pragma unroll
        for (int r = 0; r < 4; ++r) {
            l_[r] = l_[r] * alpha[r] + rs[r];
            Of0[r] *= alpha[r];
            Of1[r] *= alpha[r];
        }
        // P (C-layout) -> LDS -> A-layout; per-wave slice, no barrier needed
#pragma unroll
        for (int f = 0; f < 4; ++f)
#pragma unroll
            for (int r = 0; r < 4; ++r)
                Pw[(quad * 4 + r) * 72 + f * 16 + c] = f2bf(S[f][r]);
#pragma unroll
        for (int kc = 0; kc < 2; ++kc) {
            bf16x8 pf = *(const bf16x8*)&Pw[c * 72 + kc * 32 + quad * 8];
            bf16x8 vf0 = *(const bf16x8*)&Vt[(c) * 1024 + kb64 + kc * 32 + quad * 8];
            Of0 = __builtin_amdgcn_mfma_f32_16x16x32_bf16(pf, vf0, Of0, 0, 0, 0);
            bf16x8 vf1 = *(const bf16x8*)&Vt[(16 + c) * 1024 + kb64 + kc * 32 + quad * 8];
            Of1 = __builtin_amdgcn_mfma_f32_16x16x32_bf16(pf, vf1, Of1, 0, 0, 0);
        }
    }
#pragma unroll
    for (int r = 0; r < 4; ++r) {
        float inv = 1.f / l_[r];
        int qr = qbase + quad * 4 + r;
        size_t base = ((size_t)b * 1024 + qr) * 256 + h * 32;
        attnout[base + c]      = f2bf(Of0[r] * inv);
        attnout[base + 16 + c] = f2bf(Of1[r] * inv);
    }
}

// ---------------------------------------------------------------------------
extern "C" void kernel_launch(void* const* d_in, const int* in_sizes, int n_in,
                              void* d_out, int out_size, void* d_ws, size_t ws_size,
                              hipStream_t stream)
{
    const float* x    = (const float*)d_in[0];
    const float* wq   = (const float*)d_in[1];
    const float* wk   = (const float*)d_in[2];
    const float* wv   = (const float*)d_in[3];
    const float* gq   = (const float*)d_in[4];
    const float* bq   = (const float*)d_in[5];
    const float* gk   = (const float*)d_in[6];
    const float* bk   = (const float*)d_in[7];
    const float* gv   = (const float*)d_in[8];
    const float* bv   = (const float*)d_in[9];
    const float* btab = (const float*)d_in[10];
    const float* wo   = (const float*)d_in[11];
    const float* bo   = (const float*)d_in[12];
    float* out = (float*)d_out;

    char* w = (char*)d_ws;
    size_t off = 0;
    auto alloc = [&](size_t bytes) -> char* {
        char* p = w + off;
        off += (bytes + 255) & ~(size_t)255;
        return p;
    };
    ushort* Abuf    = (ushort*)alloc(8192ull * 2304 * 2);   // im2col patches
    ushort* Wbuf    = (ushort*)alloc(768ull * 2304 * 2);    // concat conv weights
    ushort* wo_bf   = (ushort*)alloc(65536ull * 2);         // out-proj weight
    float*  bias_r  = (float*)alloc(8ull * 3969 * 4);       // [h][dy][dx]
    float*  convf   = (float*)alloc(8192ull * 768 * 4);     // conv GEMM out (fp32)
    float*  stats   = (float*)alloc(256);                   // [proj][b][sum,sumsq]
    ushort* qb      = (ushort*)alloc(8ull * 8 * 1024 * 32 * 2);
    ushort* kb2     = (ushort*)alloc(8ull * 8 * 1024 * 32 * 2);
    ushort* vt      = (ushort*)alloc(8ull * 8 * 32 * 1024 * 2);
    ushort* attnout = (ushort*)alloc(8192ull * 256 * 2);

    hipMemsetAsync(stats, 0, 256, stream);
    pack_k<<<7293, 256, 0, stream>>>(wq, wk, wv, wo, btab, Wbuf, wo_bf, bias_r);
    im2col_k<<<256, 256, 0, stream>>>(x, Abuf);
    gemm_bt<<<dim3(64, 6), 256, 0, stream>>>(Abuf, Wbuf, 8192, 768, 2304,
                                             convf, stats, nullptr, nullptr, 0);
    gn_k<<<3072, 256, 0, stream>>>(convf, stats, gq, bq, gk, bk, gv, bv,
                                   qb, kb2, vt);
    attn_k<<<dim3(16, 64), 256, 0, stream>>>(qb, kb2, vt, bias_r, attnout);
    gemm_bt<<<dim3(2, 64), 256, 0, stream>>>(wo_bf, attnout, 256, 8192, 256,
                                             nullptr, nullptr, out, bo, 1);
}